// Round 3
// baseline (916.313 us; speedup 1.0000x reference)
//
#include <hip/hip_runtime.h>
#include <hip/hip_fp16.h>
#include <stdint.h>

// FeaturePlanes: N=1M points (INDIM=4), P=6 pairs, FDIM=16 channels, S=1025.
// out[n, p*16 + c] = bilinear(fm[p, c, :, :], x=x[n,ii[p]], y=x[n,jj[p]])
//
// R3 strategy: fm -> fmT (fp16 channel-last, 202 MB, in d_ws) as before, PLUS
// spatial bucketing of the 6M (n,p) samples by 32x32-texel tile so the sample
// pass has L1/L2 locality (R2 showed the plane re-fetched ~5x: FETCH 1.02 GB
// vs 202 MB compulsory). Records carry exact fp32 (px,py) -> math bit-identical
// to R2. Each (n,p) owns a unique out address -> deterministic output.

#define FP_S 1025
#define FP_C 16
#define FP_P 6
#define FP_TILE_SHIFT 5
#define FP_TPD 33                  // ceil(1025/32); x0 max 1024 -> tile 32
#define FP_NT (FP_TPD * FP_TPD)    // 1089 tiles per plane
#define FP_NB (FP_P * FP_NT)       // 6534 buckets total

// ---------------- utility: zero a u32 array ----------------
__global__ __launch_bounds__(256) void fp_zero(uint32_t* g, int n) {
    int i = blockIdx.x * 256 + threadIdx.x;
    if (i < n) g[i] = 0;
}

// ------------- transpose+downcast fm[p][c][y][x] fp32 -> fmT[p][y][x][c] fp16 -------------
__global__ __launch_bounds__(256) void fp_transpose_h(const float* __restrict__ fm,
                                                      __half* __restrict__ fmT) {
    const int plane = FP_S * FP_S;
    int idx = blockIdx.x * 256 + threadIdx.x;
    if (idx >= plane) return;
    int p = blockIdx.z;

    const float* src = fm + (size_t)p * FP_C * plane + idx;
    union {
        __half h[FP_C];
        float4 f4[2];
    } u;
#pragma unroll
    for (int c = 0; c < FP_C; ++c) u.h[c] = __float2half(src[(size_t)c * plane]);

    float4* dst = (float4*)(fmT + ((size_t)p * plane + idx) * FP_C);
    dst[0] = u.f4[0];
    dst[1] = u.f4[1];
}

// ---------------- per-(n,p) coordinate ----------------
__device__ __forceinline__ float2 fp_pxy(const float v[4], int a, int b) {
    float px = fminf(fmaxf((v[a] + 1.0f) * 512.0f, 0.0f), 1024.0f);
    float py = fminf(fmaxf((v[b] + 1.0f) * 512.0f, 0.0f), 1024.0f);
    return make_float2(px, py);
}

// ---------------- pass 1: histogram of bucket sizes ----------------
__global__ __launch_bounds__(256) void fp_hist(const float* __restrict__ x,
                                               uint32_t* __restrict__ ghist, int N) {
    __shared__ uint32_t lh[FP_NB];
    for (int i = threadIdx.x; i < FP_NB; i += 256) lh[i] = 0;
    __syncthreads();
    int n = blockIdx.x * 256 + threadIdx.x;
    if (n < N) {
        float4 xr = ((const float4*)x)[n];
        float v[4] = {xr.x, xr.y, xr.z, xr.w};
        int pi = 0;
#pragma unroll
        for (int a = 0; a < 3; ++a)
#pragma unroll
            for (int b = a + 1; b < 4; ++b, ++pi) {
                float2 c = fp_pxy(v, a, b);
                int tx = ((int)c.x) >> FP_TILE_SHIFT;
                int ty = ((int)c.y) >> FP_TILE_SHIFT;
                atomicAdd(&lh[pi * FP_NT + ty * FP_TPD + tx], 1u);
            }
    }
    __syncthreads();
    for (int i = threadIdx.x; i < FP_NB; i += 256)
        if (lh[i]) atomicAdd(&ghist[i], lh[i]);
}

// ---------------- pass 2: exclusive prefix sum over 6534 buckets (1 block) ----------------
#define FP_PREF_K 7  // 1024 * 7 = 7168 >= FP_NB
__global__ __launch_bounds__(1024) void fp_prefix(const uint32_t* __restrict__ ghist,
                                                  uint32_t* __restrict__ goffs) {
    __shared__ uint32_t sums[1024];
    int tid = threadIdx.x;
    uint32_t loc[FP_PREF_K];
    uint32_t s = 0;
#pragma unroll
    for (int k = 0; k < FP_PREF_K; ++k) {
        int b = tid * FP_PREF_K + k;
        uint32_t v = (b < FP_NB) ? ghist[b] : 0u;
        loc[k] = s;
        s += v;
    }
    sums[tid] = s;
    __syncthreads();
    // Hillis-Steele inclusive scan of per-thread sums
    for (int off = 1; off < 1024; off <<= 1) {
        uint32_t v = (tid >= off) ? sums[tid - off] : 0u;
        __syncthreads();
        if (tid >= off) sums[tid] += v;
        __syncthreads();
    }
    uint32_t base = (tid > 0) ? sums[tid - 1] : 0u;
#pragma unroll
    for (int k = 0; k < FP_PREF_K; ++k) {
        int b = tid * FP_PREF_K + k;
        if (b < FP_NB) goffs[b] = base + loc[k];
    }
}

// ---------------- pass 3: scatter records into bucket order ----------------
__global__ __launch_bounds__(256) void fp_scatter(const float* __restrict__ x,
                                                  uint32_t* __restrict__ goffs,
                                                  uint32_t* __restrict__ pn,
                                                  float2* __restrict__ pxy, int N) {
    int n = blockIdx.x * 256 + threadIdx.x;
    if (n >= N) return;
    float4 xr = ((const float4*)x)[n];
    float v[4] = {xr.x, xr.y, xr.z, xr.w};
    int pi = 0;
#pragma unroll
    for (int a = 0; a < 3; ++a)
#pragma unroll
        for (int b = a + 1; b < 4; ++b, ++pi) {
            float2 c = fp_pxy(v, a, b);
            int tx = ((int)c.x) >> FP_TILE_SHIFT;
            int ty = ((int)c.y) >> FP_TILE_SHIFT;
            uint32_t bk = pi * FP_NT + ty * FP_TPD + tx;
            uint32_t pos = atomicAdd(&goffs[bk], 1u);
            pn[pos] = ((uint32_t)pi << 28) | (uint32_t)n;
            pxy[pos] = c;
        }
}

// ---------------- pass 4: sample in sorted (bucket) order ----------------
__global__ __launch_bounds__(256) void fp_sample_sorted(const uint32_t* __restrict__ pn,
                                                        const float2* __restrict__ pxy,
                                                        const __half* __restrict__ fmT,
                                                        float* __restrict__ out,
                                                        int M, int swq, int swr) {
    // bijective XCD-chunked swizzle (m204): consecutive WORK ids -> same XCD L2
    int orig = blockIdx.x;
    int xcd = orig & 7;
    int ord = orig >> 3;
    int swz = (xcd < swr ? xcd * (swq + 1) : swr * (swq + 1) + (xcd - swr) * swq) + ord;
    int i = swz * 256 + threadIdx.x;
    if (i >= M) return;

    uint32_t rec = pn[i];
    int p = (int)(rec >> 28);
    int n = (int)(rec & 0x0FFFFFFFu);
    float2 c = pxy[i];
    float fx0 = floorf(c.x), fy0 = floorf(c.y);
    int x0 = (int)fx0, y0 = (int)fy0;
    int x1 = min(x0 + 1, FP_S - 1);
    int y1 = min(y0 + 1, FP_S - 1);
    float wx = c.x - fx0, wy = c.y - fy0;
    float w00 = (1.0f - wx) * (1.0f - wy);
    float w01 = wx * (1.0f - wy);
    float w10 = (1.0f - wx) * wy;
    float w11 = wx * wy;

    const size_t plane = (size_t)FP_S * FP_S;
    const __half* basep = fmT + (size_t)p * plane * FP_C;
    const float4* c00 = (const float4*)(basep + ((size_t)y0 * FP_S + x0) * FP_C);
    const float4* c01 = (const float4*)(basep + ((size_t)y0 * FP_S + x1) * FP_C);
    const float4* c10 = (const float4*)(basep + ((size_t)y1 * FP_S + x0) * FP_C);
    const float4* c11 = (const float4*)(basep + ((size_t)y1 * FP_S + x1) * FP_C);

    float4 a0 = c00[0], a1 = c00[1];
    float4 b0 = c01[0], b1 = c01[1];
    float4 g0 = c10[0], g1 = c10[1];
    float4 d0 = c11[0], d1 = c11[1];

    union {
        float4 f4;
        __half2 h2[4];
    } ua, ub, ug, ud;
    float res[FP_C];
#pragma unroll
    for (int h = 0; h < 2; ++h) {
        ua.f4 = h ? a1 : a0;
        ub.f4 = h ? b1 : b0;
        ug.f4 = h ? g1 : g0;
        ud.f4 = h ? d1 : d0;
#pragma unroll
        for (int q = 0; q < 4; ++q) {
            float2 fa = __half22float2(ua.h2[q]);
            float2 fb = __half22float2(ub.h2[q]);
            float2 fg = __half22float2(ug.h2[q]);
            float2 fd = __half22float2(ud.h2[q]);
            int cc = h * 8 + q * 2;
            res[cc]     = fa.x * w00 + fb.x * w01 + fg.x * w10 + fd.x * w11;
            res[cc + 1] = fa.y * w00 + fb.y * w01 + fg.y * w10 + fd.y * w11;
        }
    }
    float4* o = (float4*)(out + (size_t)n * (FP_P * FP_C) + p * FP_C);
#pragma unroll
    for (int k = 0; k < 4; ++k)
        o[k] = make_float4(res[4 * k], res[4 * k + 1], res[4 * k + 2], res[4 * k + 3]);
}

// ---------------- R2 fallback: unsorted sample from fmT ----------------
__device__ __forceinline__ void fp_pair(int p, int& ii, int& jj) {
    switch (p) {
        case 0: ii = 0; jj = 1; break;
        case 1: ii = 0; jj = 2; break;
        case 2: ii = 0; jj = 3; break;
        case 3: ii = 1; jj = 2; break;
        case 4: ii = 1; jj = 3; break;
        default: ii = 2; jj = 3; break;
    }
}

__global__ __launch_bounds__(256) void fp_sample_h(const float* __restrict__ xin,
                                                   const __half* __restrict__ fmT,
                                                   float* __restrict__ out, int N) {
    int n = blockIdx.x * 256 + threadIdx.x;
    if (n >= N) return;
    int p = blockIdx.z;
    int ii, jj;
    fp_pair(p, ii, jj);
    float4 xr = ((const float4*)xin)[n];
    float v[4] = {xr.x, xr.y, xr.z, xr.w};
    float2 c = fp_pxy(v, ii, jj);
    float fx0 = floorf(c.x), fy0 = floorf(c.y);
    int x0 = (int)fx0, y0 = (int)fy0;
    int x1 = min(x0 + 1, FP_S - 1);
    int y1 = min(y0 + 1, FP_S - 1);
    float wx = c.x - fx0, wy = c.y - fy0;
    float w00 = (1.0f - wx) * (1.0f - wy), w01 = wx * (1.0f - wy);
    float w10 = (1.0f - wx) * wy, w11 = wx * wy;

    const size_t plane = (size_t)FP_S * FP_S;
    const __half* basep = fmT + (size_t)p * plane * FP_C;
    const float4* c00 = (const float4*)(basep + ((size_t)y0 * FP_S + x0) * FP_C);
    const float4* c01 = (const float4*)(basep + ((size_t)y0 * FP_S + x1) * FP_C);
    const float4* c10 = (const float4*)(basep + ((size_t)y1 * FP_S + x0) * FP_C);
    const float4* c11 = (const float4*)(basep + ((size_t)y1 * FP_S + x1) * FP_C);
    float4 a0 = c00[0], a1 = c00[1];
    float4 b0 = c01[0], b1 = c01[1];
    float4 g0 = c10[0], g1 = c10[1];
    float4 d0 = c11[0], d1 = c11[1];
    union {
        float4 f4;
        __half2 h2[4];
    } ua, ub, ug, ud;
    float res[FP_C];
#pragma unroll
    for (int h = 0; h < 2; ++h) {
        ua.f4 = h ? a1 : a0;
        ub.f4 = h ? b1 : b0;
        ug.f4 = h ? g1 : g0;
        ud.f4 = h ? d1 : d0;
#pragma unroll
        for (int q = 0; q < 4; ++q) {
            float2 fa = __half22float2(ua.h2[q]);
            float2 fb = __half22float2(ub.h2[q]);
            float2 fg = __half22float2(ug.h2[q]);
            float2 fd = __half22float2(ud.h2[q]);
            int cc = h * 8 + q * 2;
            res[cc]     = fa.x * w00 + fb.x * w01 + fg.x * w10 + fd.x * w11;
            res[cc + 1] = fa.y * w00 + fb.y * w01 + fg.y * w10 + fd.y * w11;
        }
    }
    float4* o = (float4*)(out + (size_t)n * (FP_P * FP_C) + p * FP_C);
#pragma unroll
    for (int k = 0; k < 4; ++k)
        o[k] = make_float4(res[4 * k], res[4 * k + 1], res[4 * k + 2], res[4 * k + 3]);
}

// ---------------- last-resort: direct from fp32 fm ----------------
__global__ __launch_bounds__(256) void fp_sample_direct(const float* __restrict__ xin,
                                                        const float* __restrict__ fm,
                                                        float* __restrict__ out, int N) {
    int n = blockIdx.x * 256 + threadIdx.x;
    if (n >= N) return;
    int p = blockIdx.z;
    int ii, jj;
    fp_pair(p, ii, jj);
    float4 xr = ((const float4*)xin)[n];
    float v[4] = {xr.x, xr.y, xr.z, xr.w};
    float2 c = fp_pxy(v, ii, jj);
    float fx0 = floorf(c.x), fy0 = floorf(c.y);
    int x0 = (int)fx0, y0 = (int)fy0;
    int x1 = min(x0 + 1, FP_S - 1);
    int y1 = min(y0 + 1, FP_S - 1);
    float wx = c.x - fx0, wy = c.y - fy0;
    float w00 = (1.0f - wx) * (1.0f - wy), w01 = wx * (1.0f - wy);
    float w10 = (1.0f - wx) * wy, w11 = wx * wy;
    const size_t plane = (size_t)FP_S * FP_S;
    const float* pl = fm + (size_t)p * FP_C * plane;
    float res[FP_C];
#pragma unroll
    for (int cc = 0; cc < FP_C; ++cc) {
        const float* plc = pl + (size_t)cc * plane;
        float a = plc[(size_t)y0 * FP_S + x0];
        float b = plc[(size_t)y0 * FP_S + x1];
        float g = plc[(size_t)y1 * FP_S + x0];
        float d = plc[(size_t)y1 * FP_S + x1];
        res[cc] = a * w00 + b * w01 + g * w10 + d * w11;
    }
    float4* o = (float4*)(out + (size_t)n * (FP_P * FP_C) + p * FP_C);
#pragma unroll
    for (int k = 0; k < 4; ++k)
        o[k] = make_float4(res[4 * k], res[4 * k + 1], res[4 * k + 2], res[4 * k + 3]);
}

static inline size_t fp_align(size_t v) { return (v + 255) & ~(size_t)255; }

extern "C" void kernel_launch(void* const* d_in, const int* in_sizes, int n_in,
                              void* d_out, int out_size, void* d_ws, size_t ws_size,
                              hipStream_t stream) {
    const float* x = (const float*)d_in[0];
    const float* fm = (const float*)d_in[1];
    float* out = (float*)d_out;
    int N = in_sizes[0] / 4;
    int M = N * FP_P;

    const size_t plane = (size_t)FP_S * FP_S;
    const size_t fmT_bytes = (size_t)FP_P * plane * FP_C * sizeof(__half);  // ~201.7 MB

    // workspace layout for full sorted path
    size_t off_fmT = 0;
    size_t off_pn = fp_align(off_fmT + fmT_bytes);
    size_t off_pxy = fp_align(off_pn + (size_t)M * 4);
    size_t off_gh = fp_align(off_pxy + (size_t)M * 8);
    size_t off_go = fp_align(off_gh + (size_t)FP_NB * 4);
    size_t total_full = off_go + (size_t)FP_NB * 4;  // ~274 MB

    int nbN = (N + 255) / 256;

    if (ws_size >= total_full) {
        char* ws = (char*)d_ws;
        __half* fmT = (__half*)(ws + off_fmT);
        uint32_t* pn = (uint32_t*)(ws + off_pn);
        float2* pxy = (float2*)(ws + off_pxy);
        uint32_t* ghist = (uint32_t*)(ws + off_gh);
        uint32_t* goffs = (uint32_t*)(ws + off_go);

        fp_zero<<<(FP_NB + 255) / 256, 256, 0, stream>>>(ghist, FP_NB);
        dim3 gT((unsigned)((plane + 255) / 256), 1, FP_P);
        fp_transpose_h<<<gT, 256, 0, stream>>>(fm, fmT);
        fp_hist<<<nbN, 256, 0, stream>>>(x, ghist, N);
        fp_prefix<<<1, 1024, 0, stream>>>(ghist, goffs);
        fp_scatter<<<nbN, 256, 0, stream>>>(x, goffs, pn, pxy, N);

        int nwg = (M + 255) / 256;
        int swq = nwg / 8, swr = nwg % 8;
        fp_sample_sorted<<<nwg, 256, 0, stream>>>(pn, pxy, fmT, out, M, swq, swr);
    } else if (ws_size >= fmT_bytes) {
        __half* fmT = (__half*)d_ws;
        dim3 gT((unsigned)((plane + 255) / 256), 1, FP_P);
        fp_transpose_h<<<gT, 256, 0, stream>>>(fm, fmT);
        dim3 gS((unsigned)nbN, 1, FP_P);
        fp_sample_h<<<gS, 256, 0, stream>>>(x, fmT, out, N);
    } else {
        dim3 gS((unsigned)nbN, 1, FP_P);
        fp_sample_direct<<<gS, 256, 0, stream>>>(x, fm, out, N);
    }
}

// Round 4
// 848.327 us; speedup vs baseline: 1.0801x; 1.0801x over previous
//
#include <hip/hip_runtime.h>
#include <hip/hip_fp16.h>
#include <stdint.h>

// FeaturePlanes: N=1M points (INDIM=4), P=6 pairs, FDIM=16 channels, S=1025.
// out[n, p*16 + c] = bilinear(fm[p, c, :, :], x=x[n,ii[p]], y=x[n,jj[p]])
//
// R4: R2 structure (fp16 channel-last fmT in d_ws, unsorted p-major sample)
// + NON-TEMPORAL output stores. R3 proved locality is capturable (sorted
// sample FETCH=135 MB) but the sort cost too much; R2's unsorted FETCH of
// 1.02 GB (plane re-fetched ~5x despite p-major dispatch + 33.6 MB plane vs
// 256 MB L3) is attributed to the 384 MB output write stream evicting the
// plane from L3. nt-stores keep the write stream out of the caches.

#define FP_S 1025
#define FP_C 16
#define FP_P 6

typedef float f32x4 __attribute__((ext_vector_type(4)));

// ------------- transpose+downcast fm[p][c][y][x] fp32 -> fmT[p][y][x][c] fp16 -------------
__global__ __launch_bounds__(256) void fp_transpose_h(const float* __restrict__ fm,
                                                      __half* __restrict__ fmT) {
    const int plane = FP_S * FP_S;
    int idx = blockIdx.x * 256 + threadIdx.x;
    if (idx >= plane) return;
    int p = blockIdx.z;

    // reads: for each c, consecutive threads read consecutive addresses (coalesced)
    const float* src = fm + (size_t)p * FP_C * plane + idx;
    union {
        __half h[FP_C];
        f32x4 f4[2];
    } u;
#pragma unroll
    for (int c = 0; c < FP_C; ++c) u.h[c] = __float2half(src[(size_t)c * plane]);

    // writes: thread idx writes 32 B at offset idx*32 -> fully coalesced.
    // Cacheable on purpose: fmT is re-read by the sample pass right after.
    f32x4* dst = (f32x4*)(fmT + ((size_t)p * plane + idx) * FP_C);
    dst[0] = u.f4[0];
    dst[1] = u.f4[1];
}

// ---------------- shared coordinate math ----------------
__device__ __forceinline__ void fp_coords(float xv, float yv,
                                          int& x0, int& x1, int& y0, int& y1,
                                          float& w00, float& w01, float& w10, float& w11) {
    float px = fminf(fmaxf((xv + 1.0f) * 512.0f, 0.0f), 1024.0f);
    float py = fminf(fmaxf((yv + 1.0f) * 512.0f, 0.0f), 1024.0f);
    float fx0 = floorf(px), fy0 = floorf(py);
    x0 = (int)fx0;
    y0 = (int)fy0;
    x1 = min(x0 + 1, FP_S - 1);
    y1 = min(y0 + 1, FP_S - 1);
    float wx = px - fx0, wy = py - fy0;
    w00 = (1.0f - wx) * (1.0f - wy);
    w01 = wx * (1.0f - wy);
    w10 = (1.0f - wx) * wy;
    w11 = wx * wy;
}

__device__ __forceinline__ void fp_pair(int p, int& ii, int& jj) {
    // pairs: (0,1),(0,2),(0,3),(1,2),(1,3),(2,3) — p is wave-uniform (blockIdx.z)
    switch (p) {
        case 0: ii = 0; jj = 1; break;
        case 1: ii = 0; jj = 2; break;
        case 2: ii = 0; jj = 3; break;
        case 3: ii = 1; jj = 2; break;
        case 4: ii = 1; jj = 3; break;
        default: ii = 2; jj = 3; break;
    }
}

// ---------------- sample from channel-last fp16 fmT, nt output stores ----------------
__global__ __launch_bounds__(256) void fp_sample_h(const float* __restrict__ xin,
                                                   const __half* __restrict__ fmT,
                                                   float* __restrict__ out, int N) {
    int n = blockIdx.x * 256 + threadIdx.x;
    if (n >= N) return;
    int p = blockIdx.z;
    int ii, jj;
    fp_pair(p, ii, jj);

    float4 xr = ((const float4*)xin)[n];
    float xv = (ii == 0) ? xr.x : ((ii == 1) ? xr.y : xr.z);  // ii in {0,1,2}
    float yv = (jj == 1) ? xr.y : ((jj == 2) ? xr.z : xr.w);  // jj in {1,2,3}

    int x0, x1, y0, y1;
    float w00, w01, w10, w11;
    fp_coords(xv, yv, x0, x1, y0, y1, w00, w01, w10, w11);

    const size_t plane = (size_t)FP_S * FP_S;
    const __half* basep = fmT + (size_t)p * plane * FP_C;
    const f32x4* c00 = (const f32x4*)(basep + ((size_t)y0 * FP_S + x0) * FP_C);
    const f32x4* c01 = (const f32x4*)(basep + ((size_t)y0 * FP_S + x1) * FP_C);
    const f32x4* c10 = (const f32x4*)(basep + ((size_t)y1 * FP_S + x0) * FP_C);
    const f32x4* c11 = (const f32x4*)(basep + ((size_t)y1 * FP_S + x1) * FP_C);

    // issue all 8 16-B loads, then blend in fp32
    f32x4 a0 = c00[0], a1 = c00[1];
    f32x4 b0 = c01[0], b1 = c01[1];
    f32x4 g0 = c10[0], g1 = c10[1];
    f32x4 d0 = c11[0], d1 = c11[1];

    union {
        f32x4 f4;
        __half2 h2[4];
    } ua, ub, ug, ud;
    float res[FP_C];
#pragma unroll
    for (int h = 0; h < 2; ++h) {
        ua.f4 = h ? a1 : a0;
        ub.f4 = h ? b1 : b0;
        ug.f4 = h ? g1 : g0;
        ud.f4 = h ? d1 : d0;
#pragma unroll
        for (int q = 0; q < 4; ++q) {
            float2 fa = __half22float2(ua.h2[q]);
            float2 fb = __half22float2(ub.h2[q]);
            float2 fg = __half22float2(ug.h2[q]);
            float2 fd = __half22float2(ud.h2[q]);
            int c = h * 8 + q * 2;
            res[c]     = fa.x * w00 + fb.x * w01 + fg.x * w10 + fd.x * w11;
            res[c + 1] = fa.y * w00 + fb.y * w01 + fg.y * w10 + fd.y * w11;
        }
    }

    // non-temporal 64-B output write: out is write-once, never re-read —
    // keep it from evicting the fmT plane out of L2/L3.
    f32x4* o = (f32x4*)(out + (size_t)n * (FP_P * FP_C) + p * FP_C);
#pragma unroll
    for (int k = 0; k < 4; ++k) {
        f32x4 r = {res[4 * k], res[4 * k + 1], res[4 * k + 2], res[4 * k + 3]};
        __builtin_nontemporal_store(r, o + k);
    }
}

// ---------------- fallback: sample directly from channel-major fp32 fm ----------------
__global__ __launch_bounds__(256) void fp_sample_direct(const float* __restrict__ xin,
                                                        const float* __restrict__ fm,
                                                        float* __restrict__ out, int N) {
    int n = blockIdx.x * 256 + threadIdx.x;
    if (n >= N) return;
    int p = blockIdx.z;
    int ii, jj;
    fp_pair(p, ii, jj);

    float4 xr = ((const float4*)xin)[n];
    float xv = (ii == 0) ? xr.x : ((ii == 1) ? xr.y : xr.z);
    float yv = (jj == 1) ? xr.y : ((jj == 2) ? xr.z : xr.w);

    int x0, x1, y0, y1;
    float w00, w01, w10, w11;
    fp_coords(xv, yv, x0, x1, y0, y1, w00, w01, w10, w11);

    const size_t plane = (size_t)FP_S * FP_S;
    const float* pl = fm + (size_t)p * FP_C * plane;
    float res[FP_C];
#pragma unroll
    for (int c = 0; c < FP_C; ++c) {
        const float* plc = pl + (size_t)c * plane;
        float a = plc[(size_t)y0 * FP_S + x0];
        float b = plc[(size_t)y0 * FP_S + x1];
        float g = plc[(size_t)y1 * FP_S + x0];
        float d = plc[(size_t)y1 * FP_S + x1];
        res[c] = a * w00 + b * w01 + g * w10 + d * w11;
    }
    f32x4* o = (f32x4*)(out + (size_t)n * (FP_P * FP_C) + p * FP_C);
#pragma unroll
    for (int k = 0; k < 4; ++k) {
        f32x4 r = {res[4 * k], res[4 * k + 1], res[4 * k + 2], res[4 * k + 3]};
        __builtin_nontemporal_store(r, o + k);
    }
}

extern "C" void kernel_launch(void* const* d_in, const int* in_sizes, int n_in,
                              void* d_out, int out_size, void* d_ws, size_t ws_size,
                              hipStream_t stream) {
    const float* x = (const float*)d_in[0];
    const float* fm = (const float*)d_in[1];
    float* out = (float*)d_out;
    int N = in_sizes[0] / 4;

    const size_t plane = (size_t)FP_S * FP_S;
    const size_t needed = (size_t)FP_P * plane * FP_C * sizeof(__half);  // ~201.7 MB

    dim3 gS((unsigned)((N + 255) / 256), 1, FP_P);
    if (ws_size >= needed) {
        __half* fmT = (__half*)d_ws;
        dim3 gT((unsigned)((plane + 255) / 256), 1, FP_P);
        fp_transpose_h<<<gT, 256, 0, stream>>>(fm, fmT);
        fp_sample_h<<<gS, 256, 0, stream>>>(x, fmT, out, N);
    } else {
        fp_sample_direct<<<gS, 256, 0, stream>>>(x, fm, out, N);
    }
}

// Round 5
// 678.100 us; speedup vs baseline: 1.3513x; 1.2510x over previous
//
#include <hip/hip_runtime.h>
#include <hip/hip_fp16.h>
#include <stdint.h>

// FeaturePlanes: N=1M points (INDIM=4), P=6 pairs, FDIM=16 channels, S=1025.
// out[n, p*16 + c] = bilinear(fm[p, c, :, :], x=x[n,ii[p]], y=x[n,jj[p]])
//
// R5: int8 channel-last planes with PER-TEXEL fp16 scale (quantized in the
// transpose pass, no global reduction), + one fused kernel where each thread
// handles one point's 6 pairs (x read once, 384 B contiguous out per thread).
// One corner = one 16 B dwordx4 (int8x16) + 2 B scale. Footprint 113 MB vs
// R2's 202 MB -> less per-XCD L2 compulsory replication (R2 FETCH 1.02 GB
// explained as 8 split L2s each pulling ~70% of each plane).
// Precision: per-texel quant err <= amax/254 <= 2.2e-4 (fm ~ N(0,0.01)),
// convex bilinear blend preserves bound; threshold 1.0156e-3.

#define FP_S 1025
#define FP_C 16
#define FP_P 6

typedef float f32x4 __attribute__((ext_vector_type(4)));

// ------- quantize: fm[p][c][y][x] fp32 -> q8[p][y][x][c] int8 + sc[p][y][x] fp16 -------
__global__ __launch_bounds__(256) void fp_quant8(const float* __restrict__ fm,
                                                 uint4* __restrict__ q8,
                                                 __half* __restrict__ sc) {
    const int plane = FP_S * FP_S;
    int idx = blockIdx.x * 256 + threadIdx.x;
    if (idx >= plane) return;
    int p = blockIdx.z;

    const float* src = fm + (size_t)p * FP_C * plane + idx;
    float v[FP_C];
    float amax = 0.0f;
#pragma unroll
    for (int c = 0; c < FP_C; ++c) {
        v[c] = src[(size_t)c * plane];
        amax = fmaxf(amax, fabsf(v[c]));
    }
    __half h = __float2half(amax * (1.0f / 127.0f));
    float sf = __half2float(h);
    float inv = (amax > 0.0f && sf > 0.0f) ? 1.0f / sf : 0.0f;

    uint32_t w[4];
#pragma unroll
    for (int r = 0; r < 4; ++r) {
        uint32_t acc = 0;
#pragma unroll
        for (int b = 0; b < 4; ++b) {
            int q = (int)rintf(v[r * 4 + b] * inv);
            q = q > 127 ? 127 : (q < -127 ? -127 : q);
            acc |= ((uint32_t)(q & 0xff)) << (8 * b);
        }
        w[r] = acc;
    }
    size_t t = (size_t)p * plane + idx;
    q8[t] = make_uint4(w[0], w[1], w[2], w[3]);
    sc[t] = h;
}

// signed byte b of word w -> float
__device__ __forceinline__ float fp_b8(uint32_t w, int b) {
    return (float)((int)(w << (24 - 8 * b)) >> 24);
}

// ------- fused sample: one thread = one point, all 6 pairs -------
__global__ __launch_bounds__(256) void fp_fused8(const float* __restrict__ xin,
                                                 const uint4* __restrict__ q8,
                                                 const __half* __restrict__ sc,
                                                 float* __restrict__ out, int N) {
    int n = blockIdx.x * 256 + threadIdx.x;
    if (n >= N) return;

    float4 xr = ((const float4*)xin)[n];
    float v[4] = {xr.x, xr.y, xr.z, xr.w};
    const int plane = FP_S * FP_S;
    float* orow = out + (size_t)n * (FP_P * FP_C);

    int pi = 0;
#pragma unroll
    for (int a = 0; a < 3; ++a) {
#pragma unroll
        for (int b = a + 1; b < 4; ++b, ++pi) {
            float px = fminf(fmaxf((v[a] + 1.0f) * 512.0f, 0.0f), 1024.0f);
            float py = fminf(fmaxf((v[b] + 1.0f) * 512.0f, 0.0f), 1024.0f);
            float fx0 = floorf(px), fy0 = floorf(py);
            int x0 = (int)fx0, y0 = (int)fy0;
            int x1 = min(x0 + 1, FP_S - 1);
            int y1 = min(y0 + 1, FP_S - 1);
            float wx = px - fx0, wy = py - fy0;
            float w00 = (1.0f - wx) * (1.0f - wy);
            float w01 = wx * (1.0f - wy);
            float w10 = (1.0f - wx) * wy;
            float w11 = wx * wy;

            const uint4* pq = q8 + (size_t)pi * plane;
            const __half* ps = sc + (size_t)pi * plane;
            int i00 = y0 * FP_S + x0;
            int i01 = y0 * FP_S + x1;
            int i10 = y1 * FP_S + x0;
            int i11 = y1 * FP_S + x1;

            uint4 qa = pq[i00], qb = pq[i01], qc = pq[i10], qd = pq[i11];
            float wsa = w00 * __half2float(ps[i00]);
            float wsb = w01 * __half2float(ps[i01]);
            float wsc = w10 * __half2float(ps[i10]);
            float wsd = w11 * __half2float(ps[i11]);

            uint32_t wa[4] = {qa.x, qa.y, qa.z, qa.w};
            uint32_t wb[4] = {qb.x, qb.y, qb.z, qb.w};
            uint32_t wc[4] = {qc.x, qc.y, qc.z, qc.w};
            uint32_t wd[4] = {qd.x, qd.y, qd.z, qd.w};

            f32x4* o = (f32x4*)(orow + pi * FP_C);
#pragma unroll
            for (int r = 0; r < 4; ++r) {
                f32x4 rr;
#pragma unroll
                for (int bb = 0; bb < 4; ++bb) {
                    rr[bb] = wsa * fp_b8(wa[r], bb) + wsb * fp_b8(wb[r], bb) +
                             wsc * fp_b8(wc[r], bb) + wsd * fp_b8(wd[r], bb);
                }
                o[r] = rr;
            }
        }
    }
}

// ---------------- fallback: sample directly from channel-major fp32 fm ----------------
__device__ __forceinline__ void fp_pair(int p, int& ii, int& jj) {
    switch (p) {
        case 0: ii = 0; jj = 1; break;
        case 1: ii = 0; jj = 2; break;
        case 2: ii = 0; jj = 3; break;
        case 3: ii = 1; jj = 2; break;
        case 4: ii = 1; jj = 3; break;
        default: ii = 2; jj = 3; break;
    }
}

__global__ __launch_bounds__(256) void fp_sample_direct(const float* __restrict__ xin,
                                                        const float* __restrict__ fm,
                                                        float* __restrict__ out, int N) {
    int n = blockIdx.x * 256 + threadIdx.x;
    if (n >= N) return;
    int p = blockIdx.z;
    int ii, jj;
    fp_pair(p, ii, jj);

    float4 xr = ((const float4*)xin)[n];
    float xv = (ii == 0) ? xr.x : ((ii == 1) ? xr.y : xr.z);
    float yv = (jj == 1) ? xr.y : ((jj == 2) ? xr.z : xr.w);

    float px = fminf(fmaxf((xv + 1.0f) * 512.0f, 0.0f), 1024.0f);
    float py = fminf(fmaxf((yv + 1.0f) * 512.0f, 0.0f), 1024.0f);
    float fx0 = floorf(px), fy0 = floorf(py);
    int x0 = (int)fx0, y0 = (int)fy0;
    int x1 = min(x0 + 1, FP_S - 1);
    int y1 = min(y0 + 1, FP_S - 1);
    float wx = px - fx0, wy = py - fy0;
    float w00 = (1.0f - wx) * (1.0f - wy), w01 = wx * (1.0f - wy);
    float w10 = (1.0f - wx) * wy, w11 = wx * wy;

    const size_t plane = (size_t)FP_S * FP_S;
    const float* pl = fm + (size_t)p * FP_C * plane;
    float res[FP_C];
#pragma unroll
    for (int c = 0; c < FP_C; ++c) {
        const float* plc = pl + (size_t)c * plane;
        float a = plc[(size_t)y0 * FP_S + x0];
        float bq = plc[(size_t)y0 * FP_S + x1];
        float g = plc[(size_t)y1 * FP_S + x0];
        float d = plc[(size_t)y1 * FP_S + x1];
        res[c] = a * w00 + bq * w01 + g * w10 + d * w11;
    }
    f32x4* o = (f32x4*)(out + (size_t)n * (FP_P * FP_C) + p * FP_C);
#pragma unroll
    for (int k = 0; k < 4; ++k) {
        f32x4 r = {res[4 * k], res[4 * k + 1], res[4 * k + 2], res[4 * k + 3]};
        o[k] = r;
    }
}

static inline size_t fp_align(size_t v) { return (v + 255) & ~(size_t)255; }

extern "C" void kernel_launch(void* const* d_in, const int* in_sizes, int n_in,
                              void* d_out, int out_size, void* d_ws, size_t ws_size,
                              hipStream_t stream) {
    const float* x = (const float*)d_in[0];
    const float* fm = (const float*)d_in[1];
    float* out = (float*)d_out;
    int N = in_sizes[0] / 4;

    const size_t plane = (size_t)FP_S * FP_S;
    size_t q8_bytes = (size_t)FP_P * plane * 16;          // ~100.9 MB
    size_t sc_off = fp_align(q8_bytes);
    size_t needed = sc_off + (size_t)FP_P * plane * 2;    // +12.6 MB

    int nbN = (N + 255) / 256;
    if (ws_size >= needed) {
        uint4* q8 = (uint4*)d_ws;
        __half* sc = (__half*)((char*)d_ws + sc_off);
        dim3 gQ((unsigned)((plane + 255) / 256), 1, FP_P);
        fp_quant8<<<gQ, 256, 0, stream>>>(fm, q8, sc);
        fp_fused8<<<nbN, 256, 0, stream>>>(x, q8, sc, out, N);
    } else {
        dim3 gS((unsigned)nbN, 1, FP_P);
        fp_sample_direct<<<gS, 256, 0, stream>>>(x, fm, out, N);
    }
}

// Round 6
// 571.153 us; speedup vs baseline: 1.6043x; 1.1872x over previous
//
#include <hip/hip_runtime.h>
#include <hip/hip_fp16.h>
#include <stdint.h>

// FeaturePlanes: N=1M points (INDIM=4), P=6 pairs, FDIM=16 channels, S=1025.
// out[n, p*16 + c] = bilinear(fm[p, c, :, :], x=x[n,ii[p]], y=x[n,jj[p]])
//
// R6: int8 channel-last planes with PER-PLANE scale (true amax reduction) +
// p-major sample dispatch (blockIdx.z = pair). One corner = exactly one 16 B
// dwordx4, no scale gathers; active cohort footprint = one 16.8 MB plane.
// R5 showed fusing pairs (113 MB working set) inflates FETCH to 1.6 GB;
// R2 showed p-major at 33.6 MB/plane gives 1.02 GB; halving the plane
// should cut the per-XCD L2 miss replication superlinearly.
// Precision: quant err <= amax/254 ~ 2.2e-4 (fm ~ N(0,0.01) -> amax ~ 0.055),
// convex blend preserves it; threshold 1.0156e-3, fp32-exact baseline 1.2e-4.

#define FP_S 1025
#define FP_C 16
#define FP_P 6

typedef float f32x4 __attribute__((ext_vector_type(4)));

// ---------------- zero the 6 amax slots ----------------
__global__ void fp_zero6(float* g) {
    if (threadIdx.x < FP_P) g[threadIdx.x] = 0.0f;
}

// ---------------- pass 1: per-plane amax (atomicMax on uint image) ----------------
__global__ __launch_bounds__(256) void fp_amax(const float* __restrict__ fm,
                                               float* __restrict__ amax) {
    const size_t pf = (size_t)FP_C * FP_S * FP_S;  // 16,810,000 floats (div by 4)
    const size_t nf4 = pf / 4;
    int p = blockIdx.z;
    const float4* src = (const float4*)(fm + (size_t)p * pf);

    float m = 0.0f;
    for (size_t k = (size_t)blockIdx.x * 256 + threadIdx.x; k < nf4;
         k += (size_t)gridDim.x * 256) {
        float4 v = src[k];
        m = fmaxf(m, fmaxf(fmaxf(fabsf(v.x), fabsf(v.y)), fmaxf(fabsf(v.z), fabsf(v.w))));
    }
    __shared__ float red[256];
    red[threadIdx.x] = m;
    __syncthreads();
#pragma unroll
    for (int s = 128; s > 0; s >>= 1) {
        if ((int)threadIdx.x < s) red[threadIdx.x] = fmaxf(red[threadIdx.x], red[threadIdx.x + s]);
        __syncthreads();
    }
    if (threadIdx.x == 0)
        atomicMax((unsigned int*)(amax + p), __float_as_uint(red[0]));  // m >= 0
}

// ------- pass 2: quantize fm[p][c][y][x] fp32 -> q8[p][y][x][c] int8 (per-plane scale) -------
__global__ __launch_bounds__(256) void fp_quant8p(const float* __restrict__ fm,
                                                  const float* __restrict__ amax,
                                                  uint4* __restrict__ q8) {
    const int plane = FP_S * FP_S;
    int idx = blockIdx.x * 256 + threadIdx.x;
    if (idx >= plane) return;
    int p = blockIdx.z;
    float am = amax[p];
    float inv = (am > 0.0f) ? 127.0f / am : 0.0f;

    const float* src = fm + (size_t)p * FP_C * plane + idx;
    uint32_t w[4];
#pragma unroll
    for (int r = 0; r < 4; ++r) {
        uint32_t acc = 0;
#pragma unroll
        for (int b = 0; b < 4; ++b) {
            float v = src[(size_t)(r * 4 + b) * plane];
            int q = (int)rintf(v * inv);
            q = q > 127 ? 127 : (q < -127 ? -127 : q);
            acc |= ((uint32_t)(q & 0xff)) << (8 * b);
        }
        w[r] = acc;
    }
    q8[(size_t)p * plane + idx] = make_uint4(w[0], w[1], w[2], w[3]);
}

// signed byte b of word w -> float
__device__ __forceinline__ float fp_b8(uint32_t w, int b) {
    return (float)((int)(w << (24 - 8 * b)) >> 24);
}

__device__ __forceinline__ void fp_pair(int p, int& ii, int& jj) {
    // pairs: (0,1),(0,2),(0,3),(1,2),(1,3),(2,3) — p is wave-uniform (blockIdx.z)
    switch (p) {
        case 0: ii = 0; jj = 1; break;
        case 1: ii = 0; jj = 2; break;
        case 2: ii = 0; jj = 3; break;
        case 3: ii = 1; jj = 2; break;
        case 4: ii = 1; jj = 3; break;
        default: ii = 2; jj = 3; break;
    }
}

// ---------------- pass 3: p-major sample from int8 planes ----------------
__global__ __launch_bounds__(256) void fp_sample_q8(const float* __restrict__ xin,
                                                    const uint4* __restrict__ q8,
                                                    const float* __restrict__ amax,
                                                    float* __restrict__ out, int N) {
    int n = blockIdx.x * 256 + threadIdx.x;
    if (n >= N) return;
    int p = blockIdx.z;
    int ii, jj;
    fp_pair(p, ii, jj);

    float4 xr = ((const float4*)xin)[n];
    float xv = (ii == 0) ? xr.x : ((ii == 1) ? xr.y : xr.z);  // ii in {0,1,2}
    float yv = (jj == 1) ? xr.y : ((jj == 2) ? xr.z : xr.w);  // jj in {1,2,3}

    float px = fminf(fmaxf((xv + 1.0f) * 512.0f, 0.0f), 1024.0f);
    float py = fminf(fmaxf((yv + 1.0f) * 512.0f, 0.0f), 1024.0f);
    float fx0 = floorf(px), fy0 = floorf(py);
    int x0 = (int)fx0, y0 = (int)fy0;
    int x1 = min(x0 + 1, FP_S - 1);
    int y1 = min(y0 + 1, FP_S - 1);
    float wx = px - fx0, wy = py - fy0;

    float s = amax[p] * (1.0f / 127.0f);  // L2-resident 24 B array
    float w00 = (1.0f - wx) * (1.0f - wy) * s;
    float w01 = wx * (1.0f - wy) * s;
    float w10 = (1.0f - wx) * wy * s;
    float w11 = wx * wy * s;

    const int plane = FP_S * FP_S;
    const uint4* pq = q8 + (size_t)p * plane;
    uint4 qa = pq[y0 * FP_S + x0];
    uint4 qb = pq[y0 * FP_S + x1];
    uint4 qc = pq[y1 * FP_S + x0];
    uint4 qd = pq[y1 * FP_S + x1];

    uint32_t wa[4] = {qa.x, qa.y, qa.z, qa.w};
    uint32_t wb[4] = {qb.x, qb.y, qb.z, qb.w};
    uint32_t wc[4] = {qc.x, qc.y, qc.z, qc.w};
    uint32_t wd[4] = {qd.x, qd.y, qd.z, qd.w};

    f32x4* o = (f32x4*)(out + (size_t)n * (FP_P * FP_C) + p * FP_C);
#pragma unroll
    for (int r = 0; r < 4; ++r) {
        f32x4 rr;
#pragma unroll
        for (int bb = 0; bb < 4; ++bb) {
            rr[bb] = w00 * fp_b8(wa[r], bb) + w01 * fp_b8(wb[r], bb) +
                     w10 * fp_b8(wc[r], bb) + w11 * fp_b8(wd[r], bb);
        }
        o[r] = rr;
    }
}

// ---------------- fallback: sample directly from channel-major fp32 fm ----------------
__global__ __launch_bounds__(256) void fp_sample_direct(const float* __restrict__ xin,
                                                        const float* __restrict__ fm,
                                                        float* __restrict__ out, int N) {
    int n = blockIdx.x * 256 + threadIdx.x;
    if (n >= N) return;
    int p = blockIdx.z;
    int ii, jj;
    fp_pair(p, ii, jj);

    float4 xr = ((const float4*)xin)[n];
    float xv = (ii == 0) ? xr.x : ((ii == 1) ? xr.y : xr.z);
    float yv = (jj == 1) ? xr.y : ((jj == 2) ? xr.z : xr.w);

    float px = fminf(fmaxf((xv + 1.0f) * 512.0f, 0.0f), 1024.0f);
    float py = fminf(fmaxf((yv + 1.0f) * 512.0f, 0.0f), 1024.0f);
    float fx0 = floorf(px), fy0 = floorf(py);
    int x0 = (int)fx0, y0 = (int)fy0;
    int x1 = min(x0 + 1, FP_S - 1);
    int y1 = min(y0 + 1, FP_S - 1);
    float wx = px - fx0, wy = py - fy0;
    float w00 = (1.0f - wx) * (1.0f - wy), w01 = wx * (1.0f - wy);
    float w10 = (1.0f - wx) * wy, w11 = wx * wy;

    const size_t plane = (size_t)FP_S * FP_S;
    const float* pl = fm + (size_t)p * FP_C * plane;
    float res[FP_C];
#pragma unroll
    for (int c = 0; c < FP_C; ++c) {
        const float* plc = pl + (size_t)c * plane;
        float a = plc[(size_t)y0 * FP_S + x0];
        float bq = plc[(size_t)y0 * FP_S + x1];
        float g = plc[(size_t)y1 * FP_S + x0];
        float d = plc[(size_t)y1 * FP_S + x1];
        res[c] = a * w00 + bq * w01 + g * w10 + d * w11;
    }
    f32x4* o = (f32x4*)(out + (size_t)n * (FP_P * FP_C) + p * FP_C);
#pragma unroll
    for (int k = 0; k < 4; ++k) {
        f32x4 r = {res[4 * k], res[4 * k + 1], res[4 * k + 2], res[4 * k + 3]};
        o[k] = r;
    }
}

static inline size_t fp_align(size_t v) { return (v + 255) & ~(size_t)255; }

extern "C" void kernel_launch(void* const* d_in, const int* in_sizes, int n_in,
                              void* d_out, int out_size, void* d_ws, size_t ws_size,
                              hipStream_t stream) {
    const float* x = (const float*)d_in[0];
    const float* fm = (const float*)d_in[1];
    float* out = (float*)d_out;
    int N = in_sizes[0] / 4;

    const size_t plane = (size_t)FP_S * FP_S;
    size_t q8_bytes = (size_t)FP_P * plane * 16;        // ~100.9 MB
    size_t am_off = fp_align(q8_bytes);
    size_t needed = am_off + FP_P * sizeof(float);

    int nbN = (N + 255) / 256;
    if (ws_size >= needed) {
        uint4* q8 = (uint4*)d_ws;
        float* amax = (float*)((char*)d_ws + am_off);

        fp_zero6<<<1, 64, 0, stream>>>(amax);
        dim3 gA(2048, 1, FP_P);
        fp_amax<<<gA, 256, 0, stream>>>(fm, amax);
        dim3 gQ((unsigned)((plane + 255) / 256), 1, FP_P);
        fp_quant8p<<<gQ, 256, 0, stream>>>(fm, amax, q8);
        dim3 gS((unsigned)nbN, 1, FP_P);
        fp_sample_q8<<<gS, 256, 0, stream>>>(x, q8, amax, out, N);
    } else {
        dim3 gS((unsigned)nbN, 1, FP_P);
        fp_sample_direct<<<gS, 256, 0, stream>>>(x, fm, out, N);
    }
}

// Round 7
// 564.548 us; speedup vs baseline: 1.6231x; 1.0117x over previous
//
#include <hip/hip_runtime.h>
#include <stdint.h>

// FeaturePlanes: N=1M points (INDIM=4), P=6 pairs, FDIM=16 channels, S=1025.
// out[n, p*16 + c] = bilinear(fm[p, c, :, :], x=x[n,ii[p]], y=x[n,jj[p]])
//
// R7: int8 channel-last planes quantized with PER-ROW scale in ONE fused pass
// (row amax in-block, L2-hot re-read for quant: fm read from HBM once), then
// p-major sample (blockIdx.z = pair, cohort footprint = one 16.8 MB plane)
// with 2 points/thread for 8-deep gather MLP. Row scales (24.6 KB) are
// L1/L2-resident in the sample pass — no extra HBM gather stream (R5 lesson).
// Precision: quant err <= row_amax/254 <= plane_amax/254 ~ 2.2e-4; R6 measured
// absmax 3.66e-4 vs threshold 1.0156e-3.

#define FP_S 1025
#define FP_C 16
#define FP_P 6

typedef float f32x4 __attribute__((ext_vector_type(4)));

// ---- fused per-row quant: fm[p][c][y][x] fp32 -> q8[p][y][x][c] int8 + rs[p][y] ----
__global__ __launch_bounds__(256) void fp_rowquant(const float* __restrict__ fm,
                                                   uint4* __restrict__ q8,
                                                   float* __restrict__ rs) {
    const int plane = FP_S * FP_S;
    int y = blockIdx.x;
    int p = blockIdx.z;
    const float* rowbase = fm + (size_t)p * FP_C * plane + (size_t)y * FP_S;

    // phase 1: row amax over 16 channel strands (coalesced scalar loads)
    float m = 0.0f;
#pragma unroll
    for (int c = 0; c < FP_C; ++c) {
        const float* r = rowbase + (size_t)c * plane;
        for (int xx = threadIdx.x; xx < FP_S; xx += 256) m = fmaxf(m, fabsf(r[xx]));
    }
    __shared__ float red[256];
    red[threadIdx.x] = m;
    __syncthreads();
#pragma unroll
    for (int s = 128; s > 0; s >>= 1) {
        if ((int)threadIdx.x < s) red[threadIdx.x] = fmaxf(red[threadIdx.x], red[threadIdx.x + s]);
        __syncthreads();
    }
    float am = red[0];
    float inv = (am > 0.0f) ? 127.0f / am : 0.0f;
    if (threadIdx.x == 0) rs[p * FP_S + y] = am * (1.0f / 127.0f);

    // phase 2: quantize (re-reads are L2-hot; HBM sees fm only once)
    uint4* qrow = q8 + (size_t)p * plane + (size_t)y * FP_S;
    for (int xx = threadIdx.x; xx < FP_S; xx += 256) {
        uint32_t w[4];
#pragma unroll
        for (int r4 = 0; r4 < 4; ++r4) {
            uint32_t acc = 0;
#pragma unroll
            for (int b = 0; b < 4; ++b) {
                float v = rowbase[(size_t)(r4 * 4 + b) * plane + xx];
                int q = (int)rintf(v * inv);
                q = q > 127 ? 127 : (q < -127 ? -127 : q);
                acc |= ((uint32_t)(q & 0xff)) << (8 * b);
            }
            w[r4] = acc;
        }
        qrow[xx] = make_uint4(w[0], w[1], w[2], w[3]);
    }
}

// signed byte b of word w -> float
__device__ __forceinline__ float fp_b8(uint32_t w, int b) {
    return (float)((int)(w << (24 - 8 * b)) >> 24);
}

__device__ __forceinline__ void fp_pair(int p, int& ii, int& jj) {
    // pairs: (0,1),(0,2),(0,3),(1,2),(1,3),(2,3) — p is wave-uniform (blockIdx.z)
    switch (p) {
        case 0: ii = 0; jj = 1; break;
        case 1: ii = 0; jj = 2; break;
        case 2: ii = 0; jj = 3; break;
        case 3: ii = 1; jj = 2; break;
        case 4: ii = 1; jj = 3; break;
        default: ii = 2; jj = 3; break;
    }
}

// ---- p-major sample, 2 points/thread (8-deep gather MLP), per-row scales ----
__global__ __launch_bounds__(256) void fp_sample_q8r(const float* __restrict__ xin,
                                                     const uint4* __restrict__ q8,
                                                     const float* __restrict__ rs,
                                                     float* __restrict__ out, int N) {
    int i = blockIdx.x * 256 + threadIdx.x;
    int n0 = 2 * i;
    if (n0 >= N) return;
    int n1 = n0 + 1;
    bool has1 = n1 < N;

    int p = blockIdx.z;
    int ii, jj;
    fp_pair(p, ii, jj);

    const int plane = FP_S * FP_S;
    const uint4* pq = q8 + (size_t)p * plane;
    const float* prs = rs + p * FP_S;

    float4 xr[2];
    xr[0] = ((const float4*)xin)[n0];
    xr[1] = has1 ? ((const float4*)xin)[n1] : xr[0];

    int i00[2], i01[2], i10[2], i11[2];
    float W00[2], W01[2], W10[2], W11[2];
#pragma unroll
    for (int u = 0; u < 2; ++u) {
        float xv = (ii == 0) ? xr[u].x : ((ii == 1) ? xr[u].y : xr[u].z);  // ii in {0,1,2}
        float yv = (jj == 1) ? xr[u].y : ((jj == 2) ? xr[u].z : xr[u].w);  // jj in {1,2,3}
        float px = fminf(fmaxf((xv + 1.0f) * 512.0f, 0.0f), 1024.0f);
        float py = fminf(fmaxf((yv + 1.0f) * 512.0f, 0.0f), 1024.0f);
        float fx0 = floorf(px), fy0 = floorf(py);
        int x0 = (int)fx0, y0 = (int)fy0;
        int x1 = min(x0 + 1, FP_S - 1);
        int y1 = min(y0 + 1, FP_S - 1);
        float wx = px - fx0, wy = py - fy0;
        float s0 = prs[y0], s1 = prs[y1];  // L1-resident 4.1 KB array
        W00[u] = (1.0f - wx) * (1.0f - wy) * s0;
        W01[u] = wx * (1.0f - wy) * s0;
        W10[u] = (1.0f - wx) * wy * s1;
        W11[u] = wx * wy * s1;
        i00[u] = y0 * FP_S + x0;
        i01[u] = y0 * FP_S + x1;
        i10[u] = y1 * FP_S + x0;
        i11[u] = y1 * FP_S + x1;
    }

    // issue all 8 gathers before any blend
    uint4 qa[2], qb[2], qc[2], qd[2];
#pragma unroll
    for (int u = 0; u < 2; ++u) {
        qa[u] = pq[i00[u]];
        qb[u] = pq[i01[u]];
        qc[u] = pq[i10[u]];
        qd[u] = pq[i11[u]];
    }

#pragma unroll
    for (int u = 0; u < 2; ++u) {
        if (u == 1 && !has1) break;
        uint32_t wa[4] = {qa[u].x, qa[u].y, qa[u].z, qa[u].w};
        uint32_t wb[4] = {qb[u].x, qb[u].y, qb[u].z, qb[u].w};
        uint32_t wc[4] = {qc[u].x, qc[u].y, qc[u].z, qc[u].w};
        uint32_t wd[4] = {qd[u].x, qd[u].y, qd[u].z, qd[u].w};
        int n = n0 + u;
        f32x4* o = (f32x4*)(out + (size_t)n * (FP_P * FP_C) + p * FP_C);
#pragma unroll
        for (int r = 0; r < 4; ++r) {
            f32x4 rr;
#pragma unroll
            for (int bb = 0; bb < 4; ++bb) {
                rr[bb] = W00[u] * fp_b8(wa[r], bb) + W01[u] * fp_b8(wb[r], bb) +
                         W10[u] * fp_b8(wc[r], bb) + W11[u] * fp_b8(wd[r], bb);
            }
            o[r] = rr;
        }
    }
}

// ---------------- fallback: sample directly from channel-major fp32 fm ----------------
__global__ __launch_bounds__(256) void fp_sample_direct(const float* __restrict__ xin,
                                                        const float* __restrict__ fm,
                                                        float* __restrict__ out, int N) {
    int n = blockIdx.x * 256 + threadIdx.x;
    if (n >= N) return;
    int p = blockIdx.z;
    int ii, jj;
    fp_pair(p, ii, jj);

    float4 xr = ((const float4*)xin)[n];
    float xv = (ii == 0) ? xr.x : ((ii == 1) ? xr.y : xr.z);
    float yv = (jj == 1) ? xr.y : ((jj == 2) ? xr.z : xr.w);

    float px = fminf(fmaxf((xv + 1.0f) * 512.0f, 0.0f), 1024.0f);
    float py = fminf(fmaxf((yv + 1.0f) * 512.0f, 0.0f), 1024.0f);
    float fx0 = floorf(px), fy0 = floorf(py);
    int x0 = (int)fx0, y0 = (int)fy0;
    int x1 = min(x0 + 1, FP_S - 1);
    int y1 = min(y0 + 1, FP_S - 1);
    float wx = px - fx0, wy = py - fy0;
    float w00 = (1.0f - wx) * (1.0f - wy), w01 = wx * (1.0f - wy);
    float w10 = (1.0f - wx) * wy, w11 = wx * wy;

    const size_t plane = (size_t)FP_S * FP_S;
    const float* pl = fm + (size_t)p * FP_C * plane;
    float res[FP_C];
#pragma unroll
    for (int c = 0; c < FP_C; ++c) {
        const float* plc = pl + (size_t)c * plane;
        float a = plc[(size_t)y0 * FP_S + x0];
        float bq = plc[(size_t)y0 * FP_S + x1];
        float g = plc[(size_t)y1 * FP_S + x0];
        float d = plc[(size_t)y1 * FP_S + x1];
        res[c] = a * w00 + bq * w01 + g * w10 + d * w11;
    }
    f32x4* o = (f32x4*)(out + (size_t)n * (FP_P * FP_C) + p * FP_C);
#pragma unroll
    for (int k = 0; k < 4; ++k) {
        f32x4 r = {res[4 * k], res[4 * k + 1], res[4 * k + 2], res[4 * k + 3]};
        o[k] = r;
    }
}

static inline size_t fp_align(size_t v) { return (v + 255) & ~(size_t)255; }

extern "C" void kernel_launch(void* const* d_in, const int* in_sizes, int n_in,
                              void* d_out, int out_size, void* d_ws, size_t ws_size,
                              hipStream_t stream) {
    const float* x = (const float*)d_in[0];
    const float* fm = (const float*)d_in[1];
    float* out = (float*)d_out;
    int N = in_sizes[0] / 4;

    const size_t plane = (size_t)FP_S * FP_S;
    size_t q8_bytes = (size_t)FP_P * plane * 16;        // ~100.9 MB
    size_t rs_off = fp_align(q8_bytes);
    size_t needed = rs_off + (size_t)FP_P * FP_S * sizeof(float);  // +24.6 KB

    if (ws_size >= needed) {
        uint4* q8 = (uint4*)d_ws;
        float* rs = (float*)((char*)d_ws + rs_off);

        dim3 gQ(FP_S, 1, FP_P);
        fp_rowquant<<<gQ, 256, 0, stream>>>(fm, q8, rs);

        int npairs = (N + 1) / 2;
        dim3 gS((unsigned)((npairs + 255) / 256), 1, FP_P);
        fp_sample_q8r<<<gS, 256, 0, stream>>>(x, q8, rs, out, N);
    } else {
        dim3 gS((unsigned)((N + 255) / 256), 1, FP_P);
        fp_sample_direct<<<gS, 256, 0, stream>>>(x, fm, out, N);
    }
}

// Round 8
// 436.644 us; speedup vs baseline: 2.0985x; 1.2929x over previous
//
#include <hip/hip_runtime.h>
#include <stdint.h>

// FeaturePlanes: N=1M points (INDIM=4), P=6 pairs, FDIM=16 channels, S=1025.
// out[n, p*16 + c] = bilinear(fm[p, c, :, :], x=x[n,ii[p]], y=x[n,jj[p]])
//
// R8: prep = single-pass register-resident row quantizer (block = one (p,y)
// row; 16 coalesced dwordx4 loads/thread hold 4 texels x 16 channels in
// VGPRs; LDS amax reduce; quantize from registers; 64 B contiguous store).
// fm read from HBM exactly once. Sample = R6's 1-pt/thread p-major gather
// (R7's 2-pt variant regressed: write-span doubling broke L2 line merging).
// Precision: per-row scale, quant err <= row_amax/254 ~ 2.2e-4; measured
// absmax 2.44e-4 (R7) vs threshold 1.0156e-3.

#define FP_S 1025
#define FP_C 16
#define FP_P 6

typedef float f32x4 __attribute__((ext_vector_type(4)));

// ---- single-pass per-row quant: fm[p][c][y][x] fp32 -> q8[p][y][x][c] + rs[p][y] ----
__global__ __launch_bounds__(256) void fp_rowquant_v(const float* __restrict__ fm,
                                                     uint4* __restrict__ q8,
                                                     float* __restrict__ rs) {
    const size_t plane = (size_t)FP_S * FP_S;
    int y = blockIdx.x;
    int p = blockIdx.z;
    int t = threadIdx.x;
    const float* rowbase = fm + (size_t)p * FP_C * plane + (size_t)y * FP_S;

    // 16 coalesced dwordx4 loads: thread t holds texels x=4t..4t+3, all 16 channels.
    // (dwordx4 needs only 4-B alignment on gfx9; row base is 4-B aligned.)
    f32x4 v[FP_C];
    float m = 0.0f;
#pragma unroll
    for (int c = 0; c < FP_C; ++c) {
        v[c] = *(const f32x4*)(rowbase + (size_t)c * plane + 4 * t);
        m = fmaxf(m, fmaxf(fmaxf(fabsf(v[c][0]), fabsf(v[c][1])),
                           fmaxf(fabsf(v[c][2]), fabsf(v[c][3]))));
    }
    // tail texel x=1024 handled by lane 255
    float tail[FP_C];
    if (t == 255) {
#pragma unroll
        for (int c = 0; c < FP_C; ++c) {
            tail[c] = rowbase[(size_t)c * plane + 1024];
            m = fmaxf(m, fabsf(tail[c]));
        }
    }

    __shared__ float red[256];
    red[t] = m;
    __syncthreads();
#pragma unroll
    for (int s = 128; s > 0; s >>= 1) {
        if (t < s) red[t] = fmaxf(red[t], red[t + s]);
        __syncthreads();
    }
    float am = red[0];
    float inv = (am > 0.0f) ? 127.0f / am : 0.0f;
    if (t == 0) rs[p * FP_S + y] = am * (1.0f / 127.0f);

    // quantize from registers, 64 B contiguous store per thread
    uint4* qrow = q8 + (size_t)p * plane + (size_t)y * FP_S;
#pragma unroll
    for (int k = 0; k < 4; ++k) {
        uint32_t w[4];
#pragma unroll
        for (int r = 0; r < 4; ++r) {
            uint32_t acc = 0;
#pragma unroll
            for (int b = 0; b < 4; ++b) {
                int q = (int)rintf(v[4 * r + b][k] * inv);
                q = q > 127 ? 127 : (q < -127 ? -127 : q);
                acc |= ((uint32_t)(q & 0xff)) << (8 * b);
            }
            w[r] = acc;
        }
        qrow[4 * t + k] = make_uint4(w[0], w[1], w[2], w[3]);
    }
    if (t == 255) {
        uint32_t w[4];
#pragma unroll
        for (int r = 0; r < 4; ++r) {
            uint32_t acc = 0;
#pragma unroll
            for (int b = 0; b < 4; ++b) {
                int q = (int)rintf(tail[4 * r + b] * inv);
                q = q > 127 ? 127 : (q < -127 ? -127 : q);
                acc |= ((uint32_t)(q & 0xff)) << (8 * b);
            }
            w[r] = acc;
        }
        qrow[1024] = make_uint4(w[0], w[1], w[2], w[3]);
    }
}

// signed byte b of word w -> float
__device__ __forceinline__ float fp_b8(uint32_t w, int b) {
    return (float)((int)(w << (24 - 8 * b)) >> 24);
}

__device__ __forceinline__ void fp_pair(int p, int& ii, int& jj) {
    // pairs: (0,1),(0,2),(0,3),(1,2),(1,3),(2,3) — p is wave-uniform (blockIdx.z)
    switch (p) {
        case 0: ii = 0; jj = 1; break;
        case 1: ii = 0; jj = 2; break;
        case 2: ii = 0; jj = 3; break;
        case 3: ii = 1; jj = 2; break;
        case 4: ii = 1; jj = 3; break;
        default: ii = 2; jj = 3; break;
    }
}

// ---- p-major sample, 1 point/thread (R6 config), per-row scales ----
__global__ __launch_bounds__(256) void fp_sample_q8r(const float* __restrict__ xin,
                                                     const uint4* __restrict__ q8,
                                                     const float* __restrict__ rs,
                                                     float* __restrict__ out, int N) {
    int n = blockIdx.x * 256 + threadIdx.x;
    if (n >= N) return;
    int p = blockIdx.z;
    int ii, jj;
    fp_pair(p, ii, jj);

    float4 xr = ((const float4*)xin)[n];
    float xv = (ii == 0) ? xr.x : ((ii == 1) ? xr.y : xr.z);  // ii in {0,1,2}
    float yv = (jj == 1) ? xr.y : ((jj == 2) ? xr.z : xr.w);  // jj in {1,2,3}

    float px = fminf(fmaxf((xv + 1.0f) * 512.0f, 0.0f), 1024.0f);
    float py = fminf(fmaxf((yv + 1.0f) * 512.0f, 0.0f), 1024.0f);
    float fx0 = floorf(px), fy0 = floorf(py);
    int x0 = (int)fx0, y0 = (int)fy0;
    int x1 = min(x0 + 1, FP_S - 1);
    int y1 = min(y0 + 1, FP_S - 1);
    float wx = px - fx0, wy = py - fy0;

    const float* prs = rs + p * FP_S;  // 4.1 KB, L1-resident
    float s0 = prs[y0], s1 = prs[y1];
    float w00 = (1.0f - wx) * (1.0f - wy) * s0;
    float w01 = wx * (1.0f - wy) * s0;
    float w10 = (1.0f - wx) * wy * s1;
    float w11 = wx * wy * s1;

    const int plane = FP_S * FP_S;
    const uint4* pq = q8 + (size_t)p * plane;
    uint4 qa = pq[y0 * FP_S + x0];
    uint4 qb = pq[y0 * FP_S + x1];
    uint4 qc = pq[y1 * FP_S + x0];
    uint4 qd = pq[y1 * FP_S + x1];

    uint32_t wa[4] = {qa.x, qa.y, qa.z, qa.w};
    uint32_t wb[4] = {qb.x, qb.y, qb.z, qb.w};
    uint32_t wc[4] = {qc.x, qc.y, qc.z, qc.w};
    uint32_t wd[4] = {qd.x, qd.y, qd.z, qd.w};

    f32x4* o = (f32x4*)(out + (size_t)n * (FP_P * FP_C) + p * FP_C);
#pragma unroll
    for (int r = 0; r < 4; ++r) {
        f32x4 rr;
#pragma unroll
        for (int bb = 0; bb < 4; ++bb) {
            rr[bb] = w00 * fp_b8(wa[r], bb) + w01 * fp_b8(wb[r], bb) +
                     w10 * fp_b8(wc[r], bb) + w11 * fp_b8(wd[r], bb);
        }
        o[r] = rr;
    }
}

// ---------------- fallback: sample directly from channel-major fp32 fm ----------------
__global__ __launch_bounds__(256) void fp_sample_direct(const float* __restrict__ xin,
                                                        const float* __restrict__ fm,
                                                        float* __restrict__ out, int N) {
    int n = blockIdx.x * 256 + threadIdx.x;
    if (n >= N) return;
    int p = blockIdx.z;
    int ii, jj;
    fp_pair(p, ii, jj);

    float4 xr = ((const float4*)xin)[n];
    float xv = (ii == 0) ? xr.x : ((ii == 1) ? xr.y : xr.z);
    float yv = (jj == 1) ? xr.y : ((jj == 2) ? xr.z : xr.w);

    float px = fminf(fmaxf((xv + 1.0f) * 512.0f, 0.0f), 1024.0f);
    float py = fminf(fmaxf((yv + 1.0f) * 512.0f, 0.0f), 1024.0f);
    float fx0 = floorf(px), fy0 = floorf(py);
    int x0 = (int)fx0, y0 = (int)fy0;
    int x1 = min(x0 + 1, FP_S - 1);
    int y1 = min(y0 + 1, FP_S - 1);
    float wx = px - fx0, wy = py - fy0;
    float w00 = (1.0f - wx) * (1.0f - wy), w01 = wx * (1.0f - wy);
    float w10 = (1.0f - wx) * wy, w11 = wx * wy;

    const size_t plane = (size_t)FP_S * FP_S;
    const float* pl = fm + (size_t)p * FP_C * plane;
    float res[FP_C];
#pragma unroll
    for (int c = 0; c < FP_C; ++c) {
        const float* plc = pl + (size_t)c * plane;
        float a = plc[(size_t)y0 * FP_S + x0];
        float bq = plc[(size_t)y0 * FP_S + x1];
        float g = plc[(size_t)y1 * FP_S + x0];
        float d = plc[(size_t)y1 * FP_S + x1];
        res[c] = a * w00 + bq * w01 + g * w10 + d * w11;
    }
    f32x4* o = (f32x4*)(out + (size_t)n * (FP_P * FP_C) + p * FP_C);
#pragma unroll
    for (int k = 0; k < 4; ++k) {
        f32x4 r = {res[4 * k], res[4 * k + 1], res[4 * k + 2], res[4 * k + 3]};
        o[k] = r;
    }
}

static inline size_t fp_align(size_t v) { return (v + 255) & ~(size_t)255; }

extern "C" void kernel_launch(void* const* d_in, const int* in_sizes, int n_in,
                              void* d_out, int out_size, void* d_ws, size_t ws_size,
                              hipStream_t stream) {
    const float* x = (const float*)d_in[0];
    const float* fm = (const float*)d_in[1];
    float* out = (float*)d_out;
    int N = in_sizes[0] / 4;

    const size_t plane = (size_t)FP_S * FP_S;
    size_t q8_bytes = (size_t)FP_P * plane * 16;        // ~100.9 MB
    size_t rs_off = fp_align(q8_bytes);
    size_t needed = rs_off + (size_t)FP_P * FP_S * sizeof(float);  // +24.6 KB

    if (ws_size >= needed) {
        uint4* q8 = (uint4*)d_ws;
        float* rs = (float*)((char*)d_ws + rs_off);

        dim3 gQ(FP_S, 1, FP_P);
        fp_rowquant_v<<<gQ, 256, 0, stream>>>(fm, q8, rs);

        dim3 gS((unsigned)((N + 255) / 256), 1, FP_P);
        fp_sample_q8r<<<gS, 256, 0, stream>>>(x, q8, rs, out, N);
    } else {
        dim3 gS((unsigned)((N + 255) / 256), 1, FP_P);
        fp_sample_direct<<<gS, 256, 0, stream>>>(x, fm, out, N);
    }
}

// Round 9
// 429.460 us; speedup vs baseline: 2.1336x; 1.0167x over previous
//
#include <hip/hip_runtime.h>
#include <stdint.h>

// FeaturePlanes: N=1M points (INDIM=4), P=6 pairs, FDIM=16 channels, S=1025.
// out[n, p*16 + c] = bilinear(fm[p, c, :, :], x=x[n,ii[p]], y=x[n,jj[p]])
//
// R9: int8 planes stored as 2x2-texel QUADS (64 B = 4 texels x 16 ch), so a
// bilinear sample's 4 corners cluster into 1-4 adjacent 16 B slots (1 quad
// when y0,x0 both even). Intra-thread same-line loads become L1 hits and
// distinct-line touches drop ~2.5 -> ~1.9 per sample. Scales per row-pair
// rs[p][Y] (12 KB, L1-resident). Prep: block = (p,Y) row-pair, 512 threads,
// one quad/thread register-resident; fm read from HBM exactly once.
// Precision: quant err <= rowpair_amax/254 ~ 2.2e-4; threshold 1.0156e-3.

#define FP_S 1025
#define FP_C 16
#define FP_P 6
#define FP_Q 513  // quads per dim (ceil(1025/2))

typedef float f32x2 __attribute__((ext_vector_type(2)));
typedef float f32x4 __attribute__((ext_vector_type(4)));

__device__ __forceinline__ int fp_qsat(float v, float inv) {
    int q = (int)rintf(v * inv);
    return q > 127 ? 127 : (q < -127 ? -127 : q);
}

__device__ __forceinline__ uint32_t fp_q4(float a, float b, float c, float d, float inv) {
    return ((uint32_t)(fp_qsat(a, inv) & 0xff)) | ((uint32_t)(fp_qsat(b, inv) & 0xff) << 8) |
           ((uint32_t)(fp_qsat(c, inv) & 0xff) << 16) | ((uint32_t)(fp_qsat(d, inv) & 0xff) << 24);
}

__device__ __forceinline__ uint4 fp_pack16v(const f32x2* v, int comp, float inv) {
    uint4 r;
    r.x = fp_q4(v[0][comp], v[1][comp], v[2][comp], v[3][comp], inv);
    r.y = fp_q4(v[4][comp], v[5][comp], v[6][comp], v[7][comp], inv);
    r.z = fp_q4(v[8][comp], v[9][comp], v[10][comp], v[11][comp], inv);
    r.w = fp_q4(v[12][comp], v[13][comp], v[14][comp], v[15][comp], inv);
    return r;
}

__device__ __forceinline__ uint4 fp_pack16s(const float* v, float inv) {
    uint4 r;
    r.x = fp_q4(v[0], v[1], v[2], v[3], inv);
    r.y = fp_q4(v[4], v[5], v[6], v[7], inv);
    r.z = fp_q4(v[8], v[9], v[10], v[11], inv);
    r.w = fp_q4(v[12], v[13], v[14], v[15], inv);
    return r;
}

// ---- prep: fm[p][c][y][x] fp32 -> quad layout q8[p][Y][X][dy][dx][c] int8 + rs[p][Y] ----
__global__ __launch_bounds__(512) void fp_quadquant(const float* __restrict__ fm,
                                                    uint4* __restrict__ q8,
                                                    float* __restrict__ rs) {
    const size_t plane = (size_t)FP_S * FP_S;
    int Y = blockIdx.x;   // 0..512
    int p = blockIdx.z;
    int t = threadIdx.x;  // 0..511 -> quad X = t; t==0 also handles X=512
    int y0 = 2 * Y;
    bool hasy1 = (y0 + 1) < FP_S;  // false only for Y=512
    const float* pb = fm + (size_t)p * FP_C * plane;
    const float* r0 = pb + (size_t)y0 * FP_S;
    const float* r1 = hasy1 ? r0 + FP_S : r0;  // alias: dy1 slots of Y=512 are never sampled

    // one quad per thread: texels x=2t,2t+1 of rows y0,y1 (all 16 channels)
    f32x2 v0[FP_C], v1[FP_C];
    float m = 0.0f;
    int x = 2 * t;  // <= 1022, x+1 always valid
#pragma unroll
    for (int c = 0; c < FP_C; ++c) {
        v0[c] = *(const f32x2*)(r0 + (size_t)c * plane + x);
        v1[c] = *(const f32x2*)(r1 + (size_t)c * plane + x);
        m = fmaxf(m, fmaxf(fmaxf(fabsf(v0[c][0]), fabsf(v0[c][1])),
                           fmaxf(fabsf(v1[c][0]), fabsf(v1[c][1]))));
    }
    // tail column x=1024 contributes to amax (loaded again later, L1-hot)
    if (t == 0) {
#pragma unroll
        for (int c = 0; c < FP_C; ++c) {
            m = fmaxf(m, fabsf(r0[(size_t)c * plane + 1024]));
            m = fmaxf(m, fabsf(r1[(size_t)c * plane + 1024]));
        }
    }

    __shared__ float red[512];
    red[t] = m;
    __syncthreads();
#pragma unroll
    for (int s = 256; s > 0; s >>= 1) {
        if (t < s) red[t] = fmaxf(red[t], red[t + s]);
        __syncthreads();
    }
    float am = red[0];
    float inv = (am > 0.0f) ? 127.0f / am : 0.0f;
    if (t == 0) rs[p * FP_Q + Y] = am * (1.0f / 127.0f);

    // quantize from registers; 64 B contiguous store per quad
    uint4* qb_ = q8 + (((size_t)p * FP_Q + Y) * FP_Q + t) * 4;
    qb_[0] = fp_pack16v(v0, 0, inv);  // (dy0,dx0)
    qb_[1] = fp_pack16v(v0, 1, inv);  // (dy0,dx1)
    qb_[2] = fp_pack16v(v1, 0, inv);  // (dy1,dx0)
    qb_[3] = fp_pack16v(v1, 1, inv);  // (dy1,dx1)

    // tail quad X=512: only dx=0 slots are ever sampled (x<=1024)
    if (t == 0) {
        float c0[FP_C], c1[FP_C];
#pragma unroll
        for (int c = 0; c < FP_C; ++c) {
            c0[c] = r0[(size_t)c * plane + 1024];
            c1[c] = r1[(size_t)c * plane + 1024];
        }
        uint4* qt = q8 + (((size_t)p * FP_Q + Y) * FP_Q + 512) * 4;
        qt[0] = fp_pack16s(c0, inv);
        qt[1] = make_uint4(0, 0, 0, 0);
        qt[2] = fp_pack16s(c1, inv);
        qt[3] = make_uint4(0, 0, 0, 0);
    }
}

// signed byte b of word w -> float
__device__ __forceinline__ float fp_b8(uint32_t w, int b) {
    return (float)((int)(w << (24 - 8 * b)) >> 24);
}

__device__ __forceinline__ void fp_pair(int p, int& ii, int& jj) {
    // pairs: (0,1),(0,2),(0,3),(1,2),(1,3),(2,3) — p is wave-uniform (blockIdx.z)
    switch (p) {
        case 0: ii = 0; jj = 1; break;
        case 1: ii = 0; jj = 2; break;
        case 2: ii = 0; jj = 3; break;
        case 3: ii = 1; jj = 2; break;
        case 4: ii = 1; jj = 3; break;
        default: ii = 2; jj = 3; break;
    }
}

// ---- p-major sample from quad layout, 1 point/thread ----
__global__ __launch_bounds__(256) void fp_sample_qq(const float* __restrict__ xin,
                                                    const uint4* __restrict__ q8,
                                                    const float* __restrict__ rs,
                                                    float* __restrict__ out, int N) {
    int n = blockIdx.x * 256 + threadIdx.x;
    if (n >= N) return;
    int p = blockIdx.z;
    int ii, jj;
    fp_pair(p, ii, jj);

    float4 xr = ((const float4*)xin)[n];
    float xv = (ii == 0) ? xr.x : ((ii == 1) ? xr.y : xr.z);  // ii in {0,1,2}
    float yv = (jj == 1) ? xr.y : ((jj == 2) ? xr.z : xr.w);  // jj in {1,2,3}

    float px = fminf(fmaxf((xv + 1.0f) * 512.0f, 0.0f), 1024.0f);
    float py = fminf(fmaxf((yv + 1.0f) * 512.0f, 0.0f), 1024.0f);
    float fx0 = floorf(px), fy0 = floorf(py);
    int x0 = (int)fx0, y0 = (int)fy0;
    int x1 = min(x0 + 1, FP_S - 1);
    int y1 = min(y0 + 1, FP_S - 1);
    float wx = px - fx0, wy = py - fy0;

    const float* prs = rs + p * FP_Q;  // 2 KB/pair, L1-resident
    float s0 = prs[y0 >> 1], s1 = prs[y1 >> 1];
    float w00 = (1.0f - wx) * (1.0f - wy) * s0;
    float w01 = wx * (1.0f - wy) * s0;
    float w10 = (1.0f - wx) * wy * s1;
    float w11 = wx * wy * s1;

    const uint4* pq = q8 + (size_t)p * FP_Q * FP_Q * 4;
    // slot index of texel (y,x) in quad layout
    size_t ia = ((size_t)((y0 >> 1) * FP_Q + (x0 >> 1))) * 4 + ((y0 & 1) * 2 + (x0 & 1));
    size_t ib = ((size_t)((y0 >> 1) * FP_Q + (x1 >> 1))) * 4 + ((y0 & 1) * 2 + (x1 & 1));
    size_t ic = ((size_t)((y1 >> 1) * FP_Q + (x0 >> 1))) * 4 + ((y1 & 1) * 2 + (x0 & 1));
    size_t id = ((size_t)((y1 >> 1) * FP_Q + (x1 >> 1))) * 4 + ((y1 & 1) * 2 + (x1 & 1));
    uint4 qa = pq[ia];
    uint4 qb = pq[ib];
    uint4 qc = pq[ic];
    uint4 qd = pq[id];

    uint32_t wa[4] = {qa.x, qa.y, qa.z, qa.w};
    uint32_t wb[4] = {qb.x, qb.y, qb.z, qb.w};
    uint32_t wc[4] = {qc.x, qc.y, qc.z, qc.w};
    uint32_t wd[4] = {qd.x, qd.y, qd.z, qd.w};

    f32x4* o = (f32x4*)(out + (size_t)n * (FP_P * FP_C) + p * FP_C);
#pragma unroll
    for (int r = 0; r < 4; ++r) {
        f32x4 rr;
#pragma unroll
        for (int bb = 0; bb < 4; ++bb) {
            rr[bb] = w00 * fp_b8(wa[r], bb) + w01 * fp_b8(wb[r], bb) +
                     w10 * fp_b8(wc[r], bb) + w11 * fp_b8(wd[r], bb);
        }
        o[r] = rr;
    }
}

// ---------------- fallback: sample directly from channel-major fp32 fm ----------------
__global__ __launch_bounds__(256) void fp_sample_direct(const float* __restrict__ xin,
                                                        const float* __restrict__ fm,
                                                        float* __restrict__ out, int N) {
    int n = blockIdx.x * 256 + threadIdx.x;
    if (n >= N) return;
    int p = blockIdx.z;
    int ii, jj;
    fp_pair(p, ii, jj);

    float4 xr = ((const float4*)xin)[n];
    float xv = (ii == 0) ? xr.x : ((ii == 1) ? xr.y : xr.z);
    float yv = (jj == 1) ? xr.y : ((jj == 2) ? xr.z : xr.w);

    float px = fminf(fmaxf((xv + 1.0f) * 512.0f, 0.0f), 1024.0f);
    float py = fminf(fmaxf((yv + 1.0f) * 512.0f, 0.0f), 1024.0f);
    float fx0 = floorf(px), fy0 = floorf(py);
    int x0 = (int)fx0, y0 = (int)fy0;
    int x1 = min(x0 + 1, FP_S - 1);
    int y1 = min(y0 + 1, FP_S - 1);
    float wx = px - fx0, wy = py - fy0;
    float w00 = (1.0f - wx) * (1.0f - wy), w01 = wx * (1.0f - wy);
    float w10 = (1.0f - wx) * wy, w11 = wx * wy;

    const size_t plane = (size_t)FP_S * FP_S;
    const float* pl = fm + (size_t)p * FP_C * plane;
    float res[FP_C];
#pragma unroll
    for (int c = 0; c < FP_C; ++c) {
        const float* plc = pl + (size_t)c * plane;
        float a = plc[(size_t)y0 * FP_S + x0];
        float bq = plc[(size_t)y0 * FP_S + x1];
        float g = plc[(size_t)y1 * FP_S + x0];
        float d = plc[(size_t)y1 * FP_S + x1];
        res[c] = a * w00 + bq * w01 + g * w10 + d * w11;
    }
    f32x4* o = (f32x4*)(out + (size_t)n * (FP_P * FP_C) + p * FP_C);
#pragma unroll
    for (int k = 0; k < 4; ++k) {
        f32x4 r = {res[4 * k], res[4 * k + 1], res[4 * k + 2], res[4 * k + 3]};
        o[k] = r;
    }
}

static inline size_t fp_align(size_t v) { return (v + 255) & ~(size_t)255; }

extern "C" void kernel_launch(void* const* d_in, const int* in_sizes, int n_in,
                              void* d_out, int out_size, void* d_ws, size_t ws_size,
                              hipStream_t stream) {
    const float* x = (const float*)d_in[0];
    const float* fm = (const float*)d_in[1];
    float* out = (float*)d_out;
    int N = in_sizes[0] / 4;

    size_t q8_bytes = (size_t)FP_P * FP_Q * FP_Q * 64;  // ~101.1 MB
    size_t rs_off = fp_align(q8_bytes);
    size_t needed = rs_off + (size_t)FP_P * FP_Q * sizeof(float);  // +12.3 KB

    if (ws_size >= needed) {
        uint4* q8 = (uint4*)d_ws;
        float* rs = (float*)((char*)d_ws + rs_off);

        dim3 gQ(FP_Q, 1, FP_P);
        fp_quadquant<<<gQ, 512, 0, stream>>>(fm, q8, rs);

        dim3 gS((unsigned)((N + 255) / 256), 1, FP_P);
        fp_sample_qq<<<gS, 256, 0, stream>>>(x, q8, rs, out, N);
    } else {
        dim3 gS((unsigned)((N + 255) / 256), 1, FP_P);
        fp_sample_direct<<<gS, 256, 0, stream>>>(x, fm, out, N);
    }
}